// Round 5
// baseline (302.930 us; speedup 1.0000x reference)
//
#include <hip/hip_runtime.h>
#include <hip/hip_bf16.h>

#define N_NODES 50000
#define N_EDGES 800000
#define DIM 128
#define NTILES (N_EDGES / 64)   // 12500 exactly
#define SCAN_B 196              // ceil(50000/256)
#define HIST_B 3125             // 800000/256
#define NODE_B 782              // ceil(50000/64)
#define OUTZ_B 512
#define SCAT_B 2048             // 8 sets x 256 blocks; set = bid&7 -> XCD heuristic
#define WGT_B 193               // 128 composite + 1 bias + 64 W3t

typedef __bf16 bf16x8 __attribute__((ext_vector_type(8)));
typedef float f32x4 __attribute__((ext_vector_type(4)));
typedef unsigned int u32x4 __attribute__((ext_vector_type(4)));
typedef short s16x2 __attribute__((ext_vector_type(2)));

__device__ __forceinline__ unsigned short f2bf(float f) {
    unsigned u = __float_as_uint(f);
    u += 0x7fffu + ((u >> 16) & 1u);          // round-to-nearest-even
    return (unsigned short)(u >> 16);
}
__device__ __forceinline__ unsigned short f2bf_hw(float f) {
    __hip_bfloat16 h = __float2bfloat16(f);
    unsigned short s;
    __builtin_memcpy(&s, &h, 2);
    return s;
}
// packed bf16x2 add (v_pk_add_bf16 on gfx950) + relu via packed int16 max
__device__ __forceinline__ unsigned bf2_add_relu(unsigned a, unsigned b) {
    __hip_bfloat162 A, B;
    __builtin_memcpy(&A, &a, 4);
    __builtin_memcpy(&B, &b, 4);
    __hip_bfloat162 S = __hadd2(A, B);
    unsigned s;
    __builtin_memcpy(&s, &S, 4);
    s16x2 sv = __builtin_bit_cast(s16x2, s);
    s16x2 z = (s16x2){0, 0};
    return __builtin_bit_cast(unsigned, __builtin_elementwise_max(sv, z));
}

// ---- K1 (R16): composite weights + W3 transpose + dst hist + zero out.
// h = x@W1+b1 is LINEAR -> fold lin1 into the edge MLP:
//   Wa = W2[:128]-W2[128:], Wb = W2[128:]
//   gA = x@(W1@Wa) + (b1@Wa + b2),  gB = x@(W1@Wb) + b1@Wb
// blocks 0..127: Wcat/Wcbt (thread = one K=128 dot, m=bid, n=tid&127)
// block 128: bca/bcb bias dots; blocks 129..192: W3t transpose
// blocks 193..3317: hist; blocks 3318..3829: zero out
__global__ void prep_kernel(const float* __restrict__ W1, const float* __restrict__ W2,
                            const float* __restrict__ W3,
                            const float* __restrict__ b1, const float* __restrict__ b2,
                            const int* __restrict__ eidx,
                            unsigned short* __restrict__ Wcat, unsigned short* __restrict__ Wcbt,
                            unsigned short* __restrict__ W3t, float* __restrict__ bc,
                            int* __restrict__ cnt, u32x4* __restrict__ outz) {
    int bid = blockIdx.x, tid = threadIdx.x;
    if (bid < 128) {
        int m = bid;
        int n0 = tid & 127, half = tid >> 7;   // half 0 -> Wca, half 1 -> Wcb
        float acc = 0.f;
        #pragma unroll 8
        for (int k = 0; k < 128; k++) {
            float w1 = W1[m * 128 + k];                         // uniform -> s_load
            float w2b = W2[(k + 128) * 128 + n0];
            float wv = half ? w2b : (W2[k * 128 + n0] - w2b);
            acc += w1 * wv;
        }
        if (half == 0) Wcat[n0 * 128 + m] = f2bf(acc);
        else           Wcbt[n0 * 128 + m] = f2bf(acc);
    } else if (bid == 128) {
        int n0 = tid & 127, half = tid >> 7;
        float acc = half ? 0.f : b2[n0];
        #pragma unroll 8
        for (int k = 0; k < 128; k++) {
            float b1k = b1[k];                                  // uniform -> s_load
            float w2b = W2[(k + 128) * 128 + n0];
            float wv = half ? w2b : (W2[k * 128 + n0] - w2b);
            acc += b1k * wv;
        }
        bc[half * 128 + n0] = acc;
    } else if (bid < WGT_B) {
        int i = (bid - 129) * 256 + tid;      // 64 blocks cover 16384
        int k = i >> 7, n = i & 127;
        W3t[n * 128 + k] = f2bf(W3[k * 128 + n]);
    } else if (bid < WGT_B + HIST_B) {
        int e = (bid - WGT_B) * 256 + tid;    // exactly covers 800000
        atomicAdd(&cnt[eidx[N_EDGES + e]], 1);
    } else {
        int b = bid - WGT_B - HIST_B;
        u32x4 z = (u32x4){0u, 0u, 0u, 0u};
        for (int i = b * 256 + tid; i < N_NODES * DIM / 4; i += OUTZ_B * 256) outz[i] = z;
    }
}

// ---- K2 (R16): scanA (blocks 0..195) + single-stage composite node GEMM.
// No LDS (1KB scan buf only), no barriers in GEMM path: each wave owns 16 rows,
// streams x once, 64 MFMA -> gA,gB. Weights read from L2 (64KB, chip-resident).
__global__ __launch_bounds__(256, 4) void node_kernel(
        int* __restrict__ cnt, int* __restrict__ aux,
        const float* __restrict__ x,
        const unsigned short* __restrict__ Wcat, const unsigned short* __restrict__ Wcbt,
        const float* __restrict__ bc,
        unsigned short* __restrict__ gA, unsigned short* __restrict__ gB) {
    __shared__ int sbuf[256];
    int tid = threadIdx.x, bid = blockIdx.x;
    if (bid < SCAN_B) {
        int i = bid * 256 + tid;
        int v = (i < N_NODES) ? cnt[i] : 0;
        sbuf[tid] = v;
        __syncthreads();
        for (int off = 1; off < 256; off <<= 1) {
            int u = (tid >= off) ? sbuf[tid - off] : 0;
            __syncthreads();
            sbuf[tid] += u;
            __syncthreads();
        }
        if (i < N_NODES) cnt[i] = sbuf[tid] - v;
        if (tid == 255) aux[bid] = sbuf[255];
        return;
    }
    int bl = bid - SCAN_B;
    int w = tid >> 6, lane = tid & 63;
    int lr = lane & 15, q = lane >> 4;
    int row0 = bl * 64;
    int rowA = row0 + w * 16 + lr; if (rowA >= N_NODES) rowA = N_NODES - 1;

    f32x4 accA[8], accB[8];
    #pragma unroll
    for (int ct = 0; ct < 8; ct++) {
        accA[ct] = (f32x4){0.f, 0.f, 0.f, 0.f};
        accB[ct] = (f32x4){0.f, 0.f, 0.f, 0.f};
    }
    #pragma unroll
    for (int kt = 0; kt < 4; kt++) {
        const float* ap = x + (size_t)rowA * DIM + kt * 32 + q * 8;
        f32x4 x0 = *(const f32x4*)(ap);
        f32x4 x1 = *(const f32x4*)(ap + 4);
        bf16x8 a;
        #pragma unroll
        for (int j = 0; j < 4; j++) { a[j] = (__bf16)x0[j]; a[j + 4] = (__bf16)x1[j]; }
        #pragma unroll
        for (int ct = 0; ct < 8; ct++) {
            int off = (ct * 16 + lr) * 128 + kt * 32 + q * 8;
            bf16x8 bA = __builtin_bit_cast(bf16x8, *(const u32x4*)(&Wcat[off]));
            bf16x8 bB = __builtin_bit_cast(bf16x8, *(const u32x4*)(&Wcbt[off]));
            accA[ct] = __builtin_amdgcn_mfma_f32_16x16x32_bf16(a, bA, accA[ct], 0, 0, 0);
            accB[ct] = __builtin_amdgcn_mfma_f32_16x16x32_bf16(a, bB, accB[ct], 0, 0, 0);
        }
    }
    #pragma unroll
    for (int ct = 0; ct < 8; ct++) {
        int col = ct * 16 + lr;
        float ba = bc[col], bb = bc[128 + col];
        #pragma unroll
        for (int r = 0; r < 4; r++) {     // C/D: col=lane&15, row=q*4+r
            int row = row0 + w * 16 + q * 4 + r;
            if (row < N_NODES) {
                gA[(size_t)row * DIM + col] = f2bf(accA[ct][r] + ba);
                gB[(size_t)row * DIM + col] = f2bf(accB[ct][r] + bb);
            }
        }
    }
}

// ---- K3 (R12-proven): XCD-binned scatter
__global__ __launch_bounds__(256) void scatter_kernel(
        const int* __restrict__ eidx, int* __restrict__ cursor, const int* __restrict__ aux,
        int2* __restrict__ spair) {
    __shared__ int buf[256];
    int tid = threadIdx.x, bid = blockIdx.x;
    int v = (tid < SCAN_B) ? aux[tid] : 0;
    buf[tid] = v;
    __syncthreads();
    for (int off = 1; off < 256; off <<= 1) {
        int u = (tid >= off) ? buf[tid - off] : 0;
        __syncthreads();
        buf[tid] += u;
        __syncthreads();
    }
    int excl = buf[tid] - v;
    __syncthreads();
    buf[tid] = excl;
    __syncthreads();
    int set = bid & 7;
    int j = bid >> 3;
    for (int e = j * 256 + tid; e < N_EDGES; e += (SCAT_B / 8) * 256) {
        int d = eidx[N_EDGES + e];
        if (((d >> 8) & 7) == set) {
            int s = eidx[e];
            int p = atomicAdd(&cursor[d], 1) + buf[d >> 8];
            spair[p] = make_int2(s, d);
        }
    }
}

// ---- K4 (R15/R12-proven, unchanged): edge = relu(gA[dst]+gB[src]) -> GEMM2 ->
// segmented scatter-max. gB-only register prefetch under bounds(256,3).
__global__ __launch_bounds__(256, 3) void edge_kernel(
        const unsigned short* __restrict__ gA,
        const unsigned short* __restrict__ gB,
        const int2* __restrict__ spair,
        const unsigned short* __restrict__ W3t,
        const float* __restrict__ b3,
        unsigned int* __restrict__ out) {
    __shared__ __align__(16) unsigned short m1_lds[64 * 136];
    __shared__ __align__(16) unsigned short m2_lds[64 * 136];
    __shared__ int s_dst[2][64];

    int tid = threadIdx.x;
    int w = tid >> 6, lane = tid & 63;
    int lr = lane & 15, q = lane >> 4;
    int tr = tid >> 4;
    int c = (tid & 15) * 8;

    bf16x8 b3f[2][4];
    float b3v[2];
    #pragma unroll
    for (int ct = 0; ct < 2; ct++) {
        int n = (2 * w + ct) * 16 + lr;
        #pragma unroll
        for (int kt = 0; kt < 4; kt++)
            b3f[ct][kt] = __builtin_bit_cast(bf16x8, *(const u32x4*)(&W3t[n * 128 + kt * 32 + q * 8]));
        b3v[ct] = b3[n];
    }

    const int G = (int)gridDim.x;
    int tb = blockIdx.x;
    int sel = 0;

    int2 pcur[4];
    u32x4 gb_r[4];
    {
        int eb = tb * 64;
        #pragma unroll
        for (int it = 0; it < 4; it++) pcur[it] = spair[eb + tr + 16 * it];
        #pragma unroll
        for (int it = 0; it < 4; it++)
            gb_r[it] = *(const u32x4*)(&gB[(size_t)pcur[it].x * DIM + c]);
    }

    for (; tb < NTILES; tb += G) {
        #pragma unroll
        for (int it = 0; it < 4; it++) {
            int t = tr + 16 * it;
            u32x4 ga = *(const u32x4*)(&gA[(size_t)pcur[it].y * DIM + c]);
            u32x4 m;
            #pragma unroll
            for (int jj = 0; jj < 4; jj++)
                m[jj] = bf2_add_relu(ga[jj], gb_r[it][jj]);
            *(u32x4*)(&m1_lds[t * 136 + c]) = m;
        }
        if ((tid & 15) == 0) {
            #pragma unroll
            for (int it = 0; it < 4; it++) s_dst[sel][tr + 16 * it] = pcur[it].y;
        }
        __syncthreads();   // (1) m1 + s_dst ready; also orders segmax(t-1) before m2 writes(t)

        int nx = tb + G;
        int2 pnx[4];
        if (nx < NTILES) {
            int eb = nx * 64;
            #pragma unroll
            for (int it = 0; it < 4; it++) pnx[it] = spair[eb + tr + 16 * it];
            #pragma unroll
            for (int it = 0; it < 4; it++)
                gb_r[it] = *(const u32x4*)(&gB[(size_t)pnx[it].x * DIM + c]);
        }

        f32x4 acc2[4][2];
        #pragma unroll
        for (int rt = 0; rt < 4; rt++)
            #pragma unroll
            for (int ct = 0; ct < 2; ct++) acc2[rt][ct] = (f32x4){0.f, 0.f, 0.f, 0.f};
        #pragma unroll
        for (int kt = 0; kt < 4; kt++) {
            #pragma unroll
            for (int rt = 0; rt < 4; rt++) {
                bf16x8 a = __builtin_bit_cast(bf16x8,
                    *(const u32x4*)(&m1_lds[(rt * 16 + lr) * 136 + kt * 32 + q * 8]));
                acc2[rt][0] = __builtin_amdgcn_mfma_f32_16x16x32_bf16(a, b3f[0][kt], acc2[rt][0], 0, 0, 0);
                acc2[rt][1] = __builtin_amdgcn_mfma_f32_16x16x32_bf16(a, b3f[1][kt], acc2[rt][1], 0, 0, 0);
            }
        }
        #pragma unroll
        for (int rt = 0; rt < 4; rt++) {
            #pragma unroll
            for (int ct = 0; ct < 2; ct++) {
                int col = (2 * w + ct) * 16 + lr;
                #pragma unroll
                for (int r = 0; r < 4; r++)
                    m2_lds[(rt * 16 + q * 4 + r) * 136 + col] = f2bf_hw(fmaxf(acc2[rt][ct][r] + b3v[ct], 0.f));
            }
        }
        __syncthreads();   // (2) m2 ready

        if (tid < 128) {
            int pair = tid & 63;
            int g = tid >> 6;                           // == wave index (0 or 1)
            const unsigned* m2p = (const unsigned*)m2_lds;   // [64][68] dwords
            int r0 = g * 32;
            unsigned cur = m2p[r0 * 68 + pair];
            int d = s_dst[sel][r0];                     // wave-uniform
            #pragma unroll 4
            for (int i = 1; i < 32; i++) {
                int dn = s_dst[sel][r0 + i];            // wave-uniform
                unsigned v = m2p[(r0 + i) * 68 + pair];
                if (dn != d) {                          // wave-uniform branch
                    atomicMax(&out[(size_t)d * DIM + 2 * pair],     (cur & 0xffffu) << 16);
                    atomicMax(&out[(size_t)d * DIM + 2 * pair + 1], cur & 0xffff0000u);
                    d = dn; cur = v;
                } else {
                    s16x2 a2 = __builtin_bit_cast(s16x2, cur);
                    s16x2 b2 = __builtin_bit_cast(s16x2, v);
                    cur = __builtin_bit_cast(unsigned, __builtin_elementwise_max(a2, b2));
                }
            }
            atomicMax(&out[(size_t)d * DIM + 2 * pair],     (cur & 0xffffu) << 16);
            atomicMax(&out[(size_t)d * DIM + 2 * pair + 1], cur & 0xffff0000u);
        }
        // no trailing barrier: next iter's m1/s_dst[sel^1] writes don't touch m2/s_dst[sel];
        // waves 2-3 run ahead into the next staging while waves 0-1 finish segmax.

        sel ^= 1;
        #pragma unroll
        for (int it = 0; it < 4; it++) pcur[it] = pnx[it];
    }
}

extern "C" void kernel_launch(void* const* d_in, const int* in_sizes, int n_in,
                              void* d_out, int out_size, void* d_ws, size_t ws_size,
                              hipStream_t stream) {
    const float* x  = (const float*)d_in[0];
    const int* eidx = (const int*)d_in[1];
    const float* W1 = (const float*)d_in[2];
    const float* b1 = (const float*)d_in[3];
    const float* W2 = (const float*)d_in[4];
    const float* b2 = (const float*)d_in[5];
    const float* W3 = (const float*)d_in[6];
    const float* b3 = (const float*)d_in[7];

    char* ws = (char*)d_ws;
    unsigned short* gA   = (unsigned short*)ws;                    // 12,800,000 B
    unsigned short* gB   = (unsigned short*)(ws + 12800000);       // 12,800,000 B
    unsigned short* Wcat = (unsigned short*)(ws + 25600000);       // 32,768 B
    unsigned short* Wcbt = (unsigned short*)(ws + 25632768);       // 32,768 B
    unsigned short* W3t  = (unsigned short*)(ws + 25665536);       // 32,768 B
    float* bc            = (float*)(ws + 25698304);                // 1,024 B (bca|bcb)
    int* cnt             = (int*)(ws + 25699328);                  // 200,000 B
    int* aux             = (int*)(ws + 25899328);                  // 1,024 B
    int2* spair          = (int2*)(ws + 25900352);                 // 6,400,000 B -> 32,300,352 total

    (void)hipMemsetAsync(cnt, 0, N_NODES * sizeof(int), stream);
    prep_kernel<<<WGT_B + HIST_B + OUTZ_B, 256, 0, stream>>>(W1, W2, W3, b1, b2, eidx,
        Wcat, Wcbt, W3t, bc, cnt, (u32x4*)d_out);
    node_kernel<<<SCAN_B + NODE_B, 256, 0, stream>>>(cnt, aux,
        x, Wcat, Wcbt, bc, gA, gB);
    scatter_kernel<<<SCAT_B, 256, 0, stream>>>(eidx, cnt, aux, spair);
    edge_kernel<<<2048, 256, 0, stream>>>(gA, gB, spair, W3t, b3, (unsigned int*)d_out);
}

// Round 6
// 253.469 us; speedup vs baseline: 1.1951x; 1.1951x over previous
//
#include <hip/hip_runtime.h>
#include <hip/hip_bf16.h>

#define N_NODES 50000
#define N_EDGES 800000
#define DIM 128
#define NTILES (N_EDGES / 64)   // 12500 exactly
#define SCAN_B 196              // ceil(50000/256)
#define HIST_B2 2048            // XCD-binned hist: 8 sets x 256 blocks
#define NODE_B 782              // ceil(50000/64)
#define OUTZ_B 512
#define SCAT_B 2048             // 8 sets x 256 blocks; set = bid&7 -> XCD heuristic

typedef __bf16 bf16x8 __attribute__((ext_vector_type(8)));
typedef float f32x4 __attribute__((ext_vector_type(4)));
typedef unsigned int u32x4 __attribute__((ext_vector_type(4)));
typedef short s16x2 __attribute__((ext_vector_type(2)));

__device__ __forceinline__ unsigned short f2bf(float f) {
    unsigned u = __float_as_uint(f);
    u += 0x7fffu + ((u >> 16) & 1u);          // round-to-nearest-even
    return (unsigned short)(u >> 16);
}
__device__ __forceinline__ unsigned short f2bf_hw(float f) {
    __hip_bfloat16 h = __float2bfloat16(f);
    unsigned short s;
    __builtin_memcpy(&s, &h, 2);
    return s;
}
// packed bf16x2 add (v_pk_add_bf16 on gfx950) + relu via packed int16 max
__device__ __forceinline__ unsigned bf2_add_relu(unsigned a, unsigned b) {
    __hip_bfloat162 A, B;
    __builtin_memcpy(&A, &a, 4);
    __builtin_memcpy(&B, &b, 4);
    __hip_bfloat162 S = __hadd2(A, B);
    unsigned s;
    __builtin_memcpy(&s, &S, 4);
    s16x2 sv = __builtin_bit_cast(s16x2, s);
    s16x2 z = (s16x2){0, 0};
    return __builtin_bit_cast(unsigned, __builtin_elementwise_max(sv, z));
}

// ---- K0 (R17): weights only (R12-proven conversion section, 256 blocks, ~5us)
// identity: [h_i, h_j-h_i] @ W2 = h_i @ (W2a - W2b) + h_j @ W2b
__global__ void weights_kernel(const float* __restrict__ W1, const float* __restrict__ W2,
                               const float* __restrict__ W3,
                               unsigned short* __restrict__ W1t, unsigned short* __restrict__ Wat,
                               unsigned short* __restrict__ Wbt, unsigned short* __restrict__ W3t) {
    int i = blockIdx.x * 256 + threadIdx.x;
    int j = i & (DIM * DIM - 1);
    int k = j >> 7, n = j & 127;
    int sec = i >> 14;
    if (sec == 0)      W1t[n * 128 + k] = f2bf(W1[k * 128 + n]);
    else if (sec == 1) Wat[n * 128 + k] = f2bf(W2[k * 128 + n] - W2[(k + 128) * 128 + n]);
    else if (sec == 2) Wbt[n * 128 + k] = f2bf(W2[(k + 128) * 128 + n]);
    else               W3t[n * 128 + k] = f2bf(W3[k * 128 + n]);
}

// ---- K1 (R17): fused XCD-binned hist + node GEMM + zero-out.
// prep's hist was 80us at VALUBusy 0.85% (atomic-latency-bound, GPU idle) ->
// overlap the independent node GEMM into those idle cycles, and XCD-bin the
// hist atomics like the proven scatter kernel (set=bid&7 vs (d>>8)&7).
// blocks [0,2048): hist; [2048,2830): GEMM (R12-proven scan_node structure);
// [2830,3342): zero out.
__global__ __launch_bounds__(256, 2) void fused_kernel(
        const int* __restrict__ eidx, int* __restrict__ cnt,
        const float* __restrict__ x, const unsigned short* __restrict__ W1t,
        const unsigned short* __restrict__ Wat, const unsigned short* __restrict__ Wbt,
        const float* __restrict__ b1, const float* __restrict__ b2,
        unsigned short* __restrict__ gA, unsigned short* __restrict__ gB,
        u32x4* __restrict__ outz) {
    __shared__ __align__(16) unsigned short w1t[128 * 136];
    __shared__ __align__(16) unsigned short h_lds[64 * 136];
    int tid = threadIdx.x, bid = blockIdx.x;

    if (bid < HIST_B2) {
        int set = bid & 7;
        int j = bid >> 3;
        for (int e = j * 256 + tid; e < N_EDGES; e += (HIST_B2 / 8) * 256) {
            int d = eidx[N_EDGES + e];
            if (((d >> 8) & 7) == set) atomicAdd(&cnt[d], 1);
        }
        return;
    }
    if (bid >= HIST_B2 + NODE_B) {
        int b = bid - HIST_B2 - NODE_B;
        u32x4 z = (u32x4){0u, 0u, 0u, 0u};
        for (int i = b * 256 + tid; i < N_NODES * DIM / 4; i += OUTZ_B * 256) outz[i] = z;
        return;
    }

    // ---- node GEMM (R12-proven): h = bf16(x@W1+b1) -> LDS -> gA, gB
    int bl = bid - HIST_B2;
    #pragma unroll
    for (int it = 0; it < 8; it++) {
        int idx = (tid + it * 256) * 8;
        int n = idx >> 7, k = idx & 127;
        *(u32x4*)(&w1t[n * 136 + k]) = *(const u32x4*)(&W1t[idx]);
    }
    int w = tid >> 6, lane = tid & 63;
    int lr = lane & 15, q = lane >> 4;
    bf16x8 baf[2][4], bbf[2][4];
    float b2v[2];
    #pragma unroll
    for (int ct = 0; ct < 2; ct++) {
        int n = (2 * w + ct) * 16 + lr;
        #pragma unroll
        for (int kt = 0; kt < 4; kt++) {
            baf[ct][kt] = __builtin_bit_cast(bf16x8, *(const u32x4*)(&Wat[n * 128 + kt * 32 + q * 8]));
            bbf[ct][kt] = __builtin_bit_cast(bf16x8, *(const u32x4*)(&Wbt[n * 128 + kt * 32 + q * 8]));
        }
        b2v[ct] = b2[n];
    }
    __syncthreads();
    int row0 = bl * 64;
    int rowA = row0 + w * 16 + lr; if (rowA >= N_NODES) rowA = N_NODES - 1;
    {
        f32x4 acc[8];
        #pragma unroll
        for (int ct = 0; ct < 8; ct++) acc[ct] = (f32x4){0.f, 0.f, 0.f, 0.f};
        #pragma unroll
        for (int kt = 0; kt < 4; kt++) {
            const float* ap = x + (size_t)rowA * DIM + kt * 32 + q * 8;
            f32x4 x0 = *(const f32x4*)(ap);
            f32x4 x1 = *(const f32x4*)(ap + 4);
            bf16x8 a;
            #pragma unroll
            for (int j = 0; j < 4; j++) { a[j] = (__bf16)x0[j]; a[j + 4] = (__bf16)x1[j]; }
            #pragma unroll
            for (int ct = 0; ct < 8; ct++) {
                bf16x8 b = __builtin_bit_cast(bf16x8,
                    *(const u32x4*)(&w1t[(ct * 16 + lr) * 136 + kt * 32 + q * 8]));
                acc[ct] = __builtin_amdgcn_mfma_f32_16x16x32_bf16(a, b, acc[ct], 0, 0, 0);
            }
        }
        #pragma unroll
        for (int ct = 0; ct < 8; ct++) {
            int col = ct * 16 + lr;
            float bias = b1[col];
            #pragma unroll
            for (int r = 0; r < 4; r++)   // C/D: col=lane&15, row=quad*4+reg
                h_lds[(w * 16 + q * 4 + r) * 136 + col] = f2bf(acc[ct][r] + bias);
        }
    }
    __syncthreads();
    {
        f32x4 accA[4][2], accB[4][2];
        #pragma unroll
        for (int rt = 0; rt < 4; rt++)
            #pragma unroll
            for (int ct = 0; ct < 2; ct++) {
                accA[rt][ct] = (f32x4){0.f, 0.f, 0.f, 0.f};
                accB[rt][ct] = (f32x4){0.f, 0.f, 0.f, 0.f};
            }
        #pragma unroll
        for (int kt = 0; kt < 4; kt++) {
            #pragma unroll
            for (int rt = 0; rt < 4; rt++) {
                bf16x8 a = __builtin_bit_cast(bf16x8,
                    *(const u32x4*)(&h_lds[(rt * 16 + lr) * 136 + kt * 32 + q * 8]));
                accA[rt][0] = __builtin_amdgcn_mfma_f32_16x16x32_bf16(a, baf[0][kt], accA[rt][0], 0, 0, 0);
                accA[rt][1] = __builtin_amdgcn_mfma_f32_16x16x32_bf16(a, baf[1][kt], accA[rt][1], 0, 0, 0);
                accB[rt][0] = __builtin_amdgcn_mfma_f32_16x16x32_bf16(a, bbf[0][kt], accB[rt][0], 0, 0, 0);
                accB[rt][1] = __builtin_amdgcn_mfma_f32_16x16x32_bf16(a, bbf[1][kt], accB[rt][1], 0, 0, 0);
            }
        }
        #pragma unroll
        for (int rt = 0; rt < 4; rt++) {
            #pragma unroll
            for (int ct = 0; ct < 2; ct++) {
                int col = (2 * w + ct) * 16 + lr;
                #pragma unroll
                for (int r = 0; r < 4; r++) {
                    int row = row0 + rt * 16 + q * 4 + r;
                    if (row < N_NODES) {
                        gA[(size_t)row * DIM + col] = f2bf(accA[rt][ct][r] + b2v[ct]);
                        gB[(size_t)row * DIM + col] = f2bf(accB[rt][ct][r]);
                    }
                }
            }
        }
    }
}

// ---- K2 (R17): standalone scan (R12-proven logic, 196 blocks)
__global__ void scan_kernel(int* __restrict__ cnt, int* __restrict__ aux) {
    __shared__ int buf[256];
    int tid = threadIdx.x, bid = blockIdx.x;
    int i = bid * 256 + tid;
    int v = (i < N_NODES) ? cnt[i] : 0;
    buf[tid] = v;
    __syncthreads();
    for (int off = 1; off < 256; off <<= 1) {
        int u = (tid >= off) ? buf[tid - off] : 0;
        __syncthreads();
        buf[tid] += u;
        __syncthreads();
    }
    if (i < N_NODES) cnt[i] = buf[tid] - v;
    if (tid == 255) aux[bid] = buf[255];
}

// ---- K3 (R12-proven): XCD-binned scatter
__global__ __launch_bounds__(256) void scatter_kernel(
        const int* __restrict__ eidx, int* __restrict__ cursor, const int* __restrict__ aux,
        int2* __restrict__ spair) {
    __shared__ int buf[256];
    int tid = threadIdx.x, bid = blockIdx.x;
    int v = (tid < SCAN_B) ? aux[tid] : 0;
    buf[tid] = v;
    __syncthreads();
    for (int off = 1; off < 256; off <<= 1) {
        int u = (tid >= off) ? buf[tid - off] : 0;
        __syncthreads();
        buf[tid] += u;
        __syncthreads();
    }
    int excl = buf[tid] - v;
    __syncthreads();
    buf[tid] = excl;
    __syncthreads();
    int set = bid & 7;
    int j = bid >> 3;
    for (int e = j * 256 + tid; e < N_EDGES; e += (SCAT_B / 8) * 256) {
        int d = eidx[N_EDGES + e];
        if (((d >> 8) & 7) == set) {
            int s = eidx[e];
            int p = atomicAdd(&cursor[d], 1) + buf[d >> 8];
            spair[p] = make_int2(s, d);
        }
    }
}

// ---- K4 (R15/R12-proven, unchanged): edge = relu(gA[dst]+gB[src]) -> GEMM2 ->
// segmented scatter-max. gB-only register prefetch under bounds(256,3).
__global__ __launch_bounds__(256, 3) void edge_kernel(
        const unsigned short* __restrict__ gA,
        const unsigned short* __restrict__ gB,
        const int2* __restrict__ spair,
        const unsigned short* __restrict__ W3t,
        const float* __restrict__ b3,
        unsigned int* __restrict__ out) {
    __shared__ __align__(16) unsigned short m1_lds[64 * 136];
    __shared__ __align__(16) unsigned short m2_lds[64 * 136];
    __shared__ int s_dst[2][64];

    int tid = threadIdx.x;
    int w = tid >> 6, lane = tid & 63;
    int lr = lane & 15, q = lane >> 4;
    int tr = tid >> 4;
    int c = (tid & 15) * 8;

    bf16x8 b3f[2][4];
    float b3v[2];
    #pragma unroll
    for (int ct = 0; ct < 2; ct++) {
        int n = (2 * w + ct) * 16 + lr;
        #pragma unroll
        for (int kt = 0; kt < 4; kt++)
            b3f[ct][kt] = __builtin_bit_cast(bf16x8, *(const u32x4*)(&W3t[n * 128 + kt * 32 + q * 8]));
        b3v[ct] = b3[n];
    }

    const int G = (int)gridDim.x;
    int tb = blockIdx.x;
    int sel = 0;

    int2 pcur[4];
    u32x4 gb_r[4];
    {
        int eb = tb * 64;
        #pragma unroll
        for (int it = 0; it < 4; it++) pcur[it] = spair[eb + tr + 16 * it];
        #pragma unroll
        for (int it = 0; it < 4; it++)
            gb_r[it] = *(const u32x4*)(&gB[(size_t)pcur[it].x * DIM + c]);
    }

    for (; tb < NTILES; tb += G) {
        #pragma unroll
        for (int it = 0; it < 4; it++) {
            int t = tr + 16 * it;
            u32x4 ga = *(const u32x4*)(&gA[(size_t)pcur[it].y * DIM + c]);
            u32x4 m;
            #pragma unroll
            for (int jj = 0; jj < 4; jj++)
                m[jj] = bf2_add_relu(ga[jj], gb_r[it][jj]);
            *(u32x4*)(&m1_lds[t * 136 + c]) = m;
        }
        if ((tid & 15) == 0) {
            #pragma unroll
            for (int it = 0; it < 4; it++) s_dst[sel][tr + 16 * it] = pcur[it].y;
        }
        __syncthreads();   // (1) m1 + s_dst ready; also orders segmax(t-1) before m2 writes(t)

        int nx = tb + G;
        int2 pnx[4];
        if (nx < NTILES) {
            int eb = nx * 64;
            #pragma unroll
            for (int it = 0; it < 4; it++) pnx[it] = spair[eb + tr + 16 * it];
            #pragma unroll
            for (int it = 0; it < 4; it++)
                gb_r[it] = *(const u32x4*)(&gB[(size_t)pnx[it].x * DIM + c]);
        }

        f32x4 acc2[4][2];
        #pragma unroll
        for (int rt = 0; rt < 4; rt++)
            #pragma unroll
            for (int ct = 0; ct < 2; ct++) acc2[rt][ct] = (f32x4){0.f, 0.f, 0.f, 0.f};
        #pragma unroll
        for (int kt = 0; kt < 4; kt++) {
            #pragma unroll
            for (int rt = 0; rt < 4; rt++) {
                bf16x8 a = __builtin_bit_cast(bf16x8,
                    *(const u32x4*)(&m1_lds[(rt * 16 + lr) * 136 + kt * 32 + q * 8]));
                acc2[rt][0] = __builtin_amdgcn_mfma_f32_16x16x32_bf16(a, b3f[0][kt], acc2[rt][0], 0, 0, 0);
                acc2[rt][1] = __builtin_amdgcn_mfma_f32_16x16x32_bf16(a, b3f[1][kt], acc2[rt][1], 0, 0, 0);
            }
        }
        #pragma unroll
        for (int rt = 0; rt < 4; rt++) {
            #pragma unroll
            for (int ct = 0; ct < 2; ct++) {
                int col = (2 * w + ct) * 16 + lr;
                #pragma unroll
                for (int r = 0; r < 4; r++)
                    m2_lds[(rt * 16 + q * 4 + r) * 136 + col] = f2bf_hw(fmaxf(acc2[rt][ct][r] + b3v[ct], 0.f));
            }
        }
        __syncthreads();   // (2) m2 ready

        if (tid < 128) {
            int pair = tid & 63;
            int g = tid >> 6;                           // == wave index (0 or 1)
            const unsigned* m2p = (const unsigned*)m2_lds;   // [64][68] dwords
            int r0 = g * 32;
            unsigned cur = m2p[r0 * 68 + pair];
            int d = s_dst[sel][r0];                     // wave-uniform
            #pragma unroll 4
            for (int i = 1; i < 32; i++) {
                int dn = s_dst[sel][r0 + i];            // wave-uniform
                unsigned v = m2p[(r0 + i) * 68 + pair];
                if (dn != d) {                          // wave-uniform branch
                    atomicMax(&out[(size_t)d * DIM + 2 * pair],     (cur & 0xffffu) << 16);
                    atomicMax(&out[(size_t)d * DIM + 2 * pair + 1], cur & 0xffff0000u);
                    d = dn; cur = v;
                } else {
                    s16x2 a2 = __builtin_bit_cast(s16x2, cur);
                    s16x2 b2 = __builtin_bit_cast(s16x2, v);
                    cur = __builtin_bit_cast(unsigned, __builtin_elementwise_max(a2, b2));
                }
            }
            atomicMax(&out[(size_t)d * DIM + 2 * pair],     (cur & 0xffffu) << 16);
            atomicMax(&out[(size_t)d * DIM + 2 * pair + 1], cur & 0xffff0000u);
        }
        // no trailing barrier: next iter's m1/s_dst[sel^1] writes don't touch m2/s_dst[sel];
        // waves 2-3 run ahead into the next staging while waves 0-1 finish segmax.

        sel ^= 1;
        #pragma unroll
        for (int it = 0; it < 4; it++) pcur[it] = pnx[it];
    }
}

extern "C" void kernel_launch(void* const* d_in, const int* in_sizes, int n_in,
                              void* d_out, int out_size, void* d_ws, size_t ws_size,
                              hipStream_t stream) {
    const float* x  = (const float*)d_in[0];
    const int* eidx = (const int*)d_in[1];
    const float* W1 = (const float*)d_in[2];
    const float* b1 = (const float*)d_in[3];
    const float* W2 = (const float*)d_in[4];
    const float* b2 = (const float*)d_in[5];
    const float* W3 = (const float*)d_in[6];
    const float* b3 = (const float*)d_in[7];

    char* ws = (char*)d_ws;
    unsigned short* gA  = (unsigned short*)ws;                     // 12,800,000 B
    unsigned short* gB  = (unsigned short*)(ws + 12800000);        // 12,800,000 B
    unsigned short* W1t = (unsigned short*)(ws + 25600000);        // 32,768 B
    unsigned short* Wat = (unsigned short*)(ws + 25632768);        // 32,768 B
    unsigned short* Wbt = (unsigned short*)(ws + 25665536);        // 32,768 B
    unsigned short* W3t = (unsigned short*)(ws + 25698304);        // 32,768 B
    int* cnt            = (int*)(ws + 25731072);                   // 200,000 B
    int* aux            = (int*)(ws + 25931072);                   // 1,024 B
    int2* spair         = (int2*)(ws + 25932096);                  // 6,400,000 B -> 32,332,096 total

    (void)hipMemsetAsync(cnt, 0, N_NODES * sizeof(int), stream);
    weights_kernel<<<256, 256, 0, stream>>>(W1, W2, W3, W1t, Wat, Wbt, W3t);
    fused_kernel<<<HIST_B2 + NODE_B + OUTZ_B, 256, 0, stream>>>(eidx, cnt,
        x, W1t, Wat, Wbt, b1, b2, gA, gB, (u32x4*)d_out);
    scan_kernel<<<SCAN_B, 256, 0, stream>>>(cnt, aux);
    scatter_kernel<<<SCAT_B, 256, 0, stream>>>(eidx, cnt, aux, spair);
    edge_kernel<<<2048, 256, 0, stream>>>(gA, gB, spair, W3t, b3, (unsigned int*)d_out);
}

// Round 7
// 205.108 us; speedup vs baseline: 1.4769x; 1.2358x over previous
//
#include <hip/hip_runtime.h>
#include <hip/hip_bf16.h>

#define N_NODES 50000
#define N_EDGES 800000
#define DIM 128
#define NTILES (N_EDGES / 64)   // 12500 exactly
#define NODE_B 782              // ceil(50000/64)
#define CNT_B 256               // count blocks (LDS hist, no atomics)
#define OUTZ_B 512
#define NBIN 196                // ceil(50000/256) coarse buckets (dst>>8)
#define E_PER_CBLK 3125         // 800000/256
#define CAP 7680                // per-bucket LDS sort capacity (mean 4096, +56 sigma)

typedef __bf16 bf16x8 __attribute__((ext_vector_type(8)));
typedef float f32x4 __attribute__((ext_vector_type(4)));
typedef unsigned int u32x4 __attribute__((ext_vector_type(4)));
typedef short s16x2 __attribute__((ext_vector_type(2)));

__device__ __forceinline__ unsigned short f2bf(float f) {
    unsigned u = __float_as_uint(f);
    u += 0x7fffu + ((u >> 16) & 1u);          // round-to-nearest-even
    return (unsigned short)(u >> 16);
}
__device__ __forceinline__ unsigned short f2bf_hw(float f) {
    __hip_bfloat16 h = __float2bfloat16(f);
    unsigned short s;
    __builtin_memcpy(&s, &h, 2);
    return s;
}
// packed bf16x2 add (v_pk_add_bf16 on gfx950) + relu via packed int16 max
__device__ __forceinline__ unsigned bf2_add_relu(unsigned a, unsigned b) {
    __hip_bfloat162 A, B;
    __builtin_memcpy(&A, &a, 4);
    __builtin_memcpy(&B, &b, 4);
    __hip_bfloat162 S = __hadd2(A, B);
    unsigned s;
    __builtin_memcpy(&s, &S, 4);
    s16x2 sv = __builtin_bit_cast(s16x2, s);
    s16x2 z = (s16x2){0, 0};
    return __builtin_bit_cast(unsigned, __builtin_elementwise_max(sv, z));
}

// ---- K0 (R12-proven): weight conversion
__global__ void weights_kernel(const float* __restrict__ W1, const float* __restrict__ W2,
                               const float* __restrict__ W3,
                               unsigned short* __restrict__ W1t, unsigned short* __restrict__ Wat,
                               unsigned short* __restrict__ Wbt, unsigned short* __restrict__ W3t) {
    int i = blockIdx.x * 256 + threadIdx.x;
    int j = i & (DIM * DIM - 1);
    int k = j >> 7, n = j & 127;
    int sec = i >> 14;
    if (sec == 0)      W1t[n * 128 + k] = f2bf(W1[k * 128 + n]);
    else if (sec == 1) Wat[n * 128 + k] = f2bf(W2[k * 128 + n] - W2[(k + 128) * 128 + n]);
    else if (sec == 2) Wbt[n * 128 + k] = f2bf(W2[(k + 128) * 128 + n]);
    else               W3t[n * 128 + k] = f2bf(W3[k * 128 + n]);
}

// ---- K1 (R18): node GEMM (R12-proven) + LDS coarse count (NO global atomics) + zero-out.
// blocks [0,782): GEMM; [782,1038): count -> counts[bin][block]; [1038,1550): zero out.
__global__ __launch_bounds__(256, 2) void fused_kernel(
        const int* __restrict__ eidx, int* __restrict__ counts,
        const float* __restrict__ x, const unsigned short* __restrict__ W1t,
        const unsigned short* __restrict__ Wat, const unsigned short* __restrict__ Wbt,
        const float* __restrict__ b1, const float* __restrict__ b2,
        unsigned short* __restrict__ gA, unsigned short* __restrict__ gB,
        u32x4* __restrict__ outz) {
    __shared__ __align__(16) unsigned short w1t[128 * 136];
    __shared__ __align__(16) unsigned short h_lds[64 * 136];
    int tid = threadIdx.x, bid = blockIdx.x;

    if (bid >= NODE_B && bid < NODE_B + CNT_B) {
        // coarse histogram of dst>>8 for this block's contiguous edge chunk
        int cblk = bid - NODE_B;
        int* hh = (int*)w1t;
        hh[tid] = 0;
        __syncthreads();
        int base = cblk * E_PER_CBLK;
        #pragma unroll
        for (int i = 0; i < 13; i++) {
            int idx = i * 256 + tid;
            if (idx < E_PER_CBLK)
                atomicAdd(&hh[eidx[N_EDGES + base + idx] >> 8], 1);
        }
        __syncthreads();
        counts[tid * 256 + cblk] = hh[tid];     // [bin][block]
        return;
    }
    if (bid >= NODE_B + CNT_B) {
        int b = bid - NODE_B - CNT_B;
        u32x4 z = (u32x4){0u, 0u, 0u, 0u};
        for (int i = b * 256 + tid; i < N_NODES * DIM / 4; i += OUTZ_B * 256) outz[i] = z;
        return;
    }

    // ---- node GEMM (R12-proven): h = bf16(x@W1+b1) -> LDS -> gA, gB
    int bl = bid;
    #pragma unroll
    for (int it = 0; it < 8; it++) {
        int idx = (tid + it * 256) * 8;
        int n = idx >> 7, k = idx & 127;
        *(u32x4*)(&w1t[n * 136 + k]) = *(const u32x4*)(&W1t[idx]);
    }
    int w = tid >> 6, lane = tid & 63;
    int lr = lane & 15, q = lane >> 4;
    bf16x8 baf[2][4], bbf[2][4];
    float b2v[2];
    #pragma unroll
    for (int ct = 0; ct < 2; ct++) {
        int n = (2 * w + ct) * 16 + lr;
        #pragma unroll
        for (int kt = 0; kt < 4; kt++) {
            baf[ct][kt] = __builtin_bit_cast(bf16x8, *(const u32x4*)(&Wat[n * 128 + kt * 32 + q * 8]));
            bbf[ct][kt] = __builtin_bit_cast(bf16x8, *(const u32x4*)(&Wbt[n * 128 + kt * 32 + q * 8]));
        }
        b2v[ct] = b2[n];
    }
    __syncthreads();
    int row0 = bl * 64;
    int rowA = row0 + w * 16 + lr; if (rowA >= N_NODES) rowA = N_NODES - 1;
    {
        f32x4 acc[8];
        #pragma unroll
        for (int ct = 0; ct < 8; ct++) acc[ct] = (f32x4){0.f, 0.f, 0.f, 0.f};
        #pragma unroll
        for (int kt = 0; kt < 4; kt++) {
            const float* ap = x + (size_t)rowA * DIM + kt * 32 + q * 8;
            f32x4 x0 = *(const f32x4*)(ap);
            f32x4 x1 = *(const f32x4*)(ap + 4);
            bf16x8 a;
            #pragma unroll
            for (int j = 0; j < 4; j++) { a[j] = (__bf16)x0[j]; a[j + 4] = (__bf16)x1[j]; }
            #pragma unroll
            for (int ct = 0; ct < 8; ct++) {
                bf16x8 b = __builtin_bit_cast(bf16x8,
                    *(const u32x4*)(&w1t[(ct * 16 + lr) * 136 + kt * 32 + q * 8]));
                acc[ct] = __builtin_amdgcn_mfma_f32_16x16x32_bf16(a, b, acc[ct], 0, 0, 0);
            }
        }
        #pragma unroll
        for (int ct = 0; ct < 8; ct++) {
            int col = ct * 16 + lr;
            float bias = b1[col];
            #pragma unroll
            for (int r = 0; r < 4; r++)   // C/D: col=lane&15, row=quad*4+reg
                h_lds[(w * 16 + q * 4 + r) * 136 + col] = f2bf(acc[ct][r] + bias);
        }
    }
    __syncthreads();
    {
        f32x4 accA[4][2], accB[4][2];
        #pragma unroll
        for (int rt = 0; rt < 4; rt++)
            #pragma unroll
            for (int ct = 0; ct < 2; ct++) {
                accA[rt][ct] = (f32x4){0.f, 0.f, 0.f, 0.f};
                accB[rt][ct] = (f32x4){0.f, 0.f, 0.f, 0.f};
            }
        #pragma unroll
        for (int kt = 0; kt < 4; kt++) {
            #pragma unroll
            for (int rt = 0; rt < 4; rt++) {
                bf16x8 a = __builtin_bit_cast(bf16x8,
                    *(const u32x4*)(&h_lds[(rt * 16 + lr) * 136 + kt * 32 + q * 8]));
                accA[rt][0] = __builtin_amdgcn_mfma_f32_16x16x32_bf16(a, baf[0][kt], accA[rt][0], 0, 0, 0);
                accA[rt][1] = __builtin_amdgcn_mfma_f32_16x16x32_bf16(a, baf[1][kt], accA[rt][1], 0, 0, 0);
                accB[rt][0] = __builtin_amdgcn_mfma_f32_16x16x32_bf16(a, bbf[0][kt], accB[rt][0], 0, 0, 0);
                accB[rt][1] = __builtin_amdgcn_mfma_f32_16x16x32_bf16(a, bbf[1][kt], accB[rt][1], 0, 0, 0);
            }
        }
        #pragma unroll
        for (int rt = 0; rt < 4; rt++) {
            #pragma unroll
            for (int ct = 0; ct < 2; ct++) {
                int col = (2 * w + ct) * 16 + lr;
                #pragma unroll
                for (int r = 0; r < 4; r++) {
                    int row = row0 + rt * 16 + q * 4 + r;
                    if (row < N_NODES) {
                        gA[(size_t)row * DIM + col] = f2bf(accA[rt][ct][r] + b2v[ct]);
                        gB[(size_t)row * DIM + col] = f2bf(accB[rt][ct][r]);
                    }
                }
            }
        }
    }
}

// ---- K2 (R18): per-bin exclusive scan over blocks (in-place) + bin totals
__global__ void scanA_kernel(int* __restrict__ counts, int* __restrict__ binsum) {
    __shared__ int buf[256];
    int tid = threadIdx.x, b = blockIdx.x;   // b = bin
    int v = counts[b * 256 + tid];
    buf[tid] = v;
    __syncthreads();
    for (int off = 1; off < 256; off <<= 1) {
        int u = (tid >= off) ? buf[tid - off] : 0;
        __syncthreads();
        buf[tid] += u;
        __syncthreads();
    }
    counts[b * 256 + tid] = buf[tid] - v;     // exclusive prefix over blocks
    if (tid == 255) binsum[b] = buf[255];
}

// ---- K3 (R18): exclusive scan of bin totals -> binbase[0..NBIN]
__global__ void scanB_kernel(const int* __restrict__ binsum, int* __restrict__ binbase) {
    __shared__ int buf[256];
    int tid = threadIdx.x;
    int v = (tid < NBIN) ? binsum[tid] : 0;
    buf[tid] = v;
    __syncthreads();
    for (int off = 1; off < 256; off <<= 1) {
        int u = (tid >= off) ? buf[tid - off] : 0;
        __syncthreads();
        buf[tid] += u;
        __syncthreads();
    }
    binbase[tid] = buf[tid] - v;              // exclusive; binbase[NBIN] = 800000
    if (tid == 255) binbase[256] = buf[255];
}

// ---- K4 (R18): coarse scatter into dst>>8 buckets. Pre-reserved disjoint ranges
// per (block,bin) -> LDS cursors only, ZERO global atomics.
__global__ __launch_bounds__(256) void cscatter_kernel(
        const int* __restrict__ eidx, const int* __restrict__ counts,
        const int* __restrict__ binbase, int2* __restrict__ spair) {
    __shared__ int lcur[256];
    int tid = threadIdx.x, blk = blockIdx.x;
    lcur[tid] = (tid < NBIN) ? (binbase[tid] + counts[tid * 256 + blk]) : 0;
    __syncthreads();
    int base = blk * E_PER_CBLK;
    #pragma unroll
    for (int i = 0; i < 13; i++) {
        int idx = i * 256 + tid;
        if (idx < E_PER_CBLK) {
            int e = base + idx;
            int d = eidx[N_EDGES + e];
            int s = eidx[e];
            int p = atomicAdd(&lcur[d >> 8], 1);   // LDS atomic
            spair[p] = make_int2(s, d);
        }
    }
}

// ---- K5 (R18): per-bucket LDS sort by dst&255 -> fully dst-grouped spair (in place).
// Overflow beyond CAP leaves edges unsorted within the bucket: still CORRECT
// (segmax handles arbitrary boundaries via atomics), only slower. mean n=4096.
__global__ __launch_bounds__(256) void bsort_kernel(
        const int* __restrict__ binbase, int2* __restrict__ spair) {
    __shared__ int2 el[CAP];
    __shared__ int h[256];
    __shared__ int cum[256];
    int tid = threadIdx.x, b = blockIdx.x;
    int start = binbase[b];
    int n = binbase[b + 1] - start;
    int nn = (n < CAP) ? n : CAP;
    for (int i = tid; i < nn; i += 256) el[i] = spair[start + i];
    h[tid] = 0;
    __syncthreads();
    for (int i = tid; i < nn; i += 256) atomicAdd(&h[el[i].y & 255], 1);
    __syncthreads();
    int v = h[tid];
    cum[tid] = v;
    __syncthreads();
    for (int off = 1; off < 256; off <<= 1) {
        int u = (tid >= off) ? cum[tid - off] : 0;
        __syncthreads();
        cum[tid] += u;
        __syncthreads();
    }
    cum[tid] -= v;                            // exclusive
    __syncthreads();
    for (int i = tid; i < nn; i += 256) {
        int2 e = el[i];
        int p = start + atomicAdd(&cum[e.y & 255], 1);
        spair[p] = e;
    }
}

// ---- K6 (R15/R12-proven, unchanged): edge = relu(gA[dst]+gB[src]) -> GEMM2 ->
// segmented scatter-max. gB-only register prefetch under bounds(256,3).
__global__ __launch_bounds__(256, 3) void edge_kernel(
        const unsigned short* __restrict__ gA,
        const unsigned short* __restrict__ gB,
        const int2* __restrict__ spair,
        const unsigned short* __restrict__ W3t,
        const float* __restrict__ b3,
        unsigned int* __restrict__ out) {
    __shared__ __align__(16) unsigned short m1_lds[64 * 136];
    __shared__ __align__(16) unsigned short m2_lds[64 * 136];
    __shared__ int s_dst[2][64];

    int tid = threadIdx.x;
    int w = tid >> 6, lane = tid & 63;
    int lr = lane & 15, q = lane >> 4;
    int tr = tid >> 4;
    int c = (tid & 15) * 8;

    bf16x8 b3f[2][4];
    float b3v[2];
    #pragma unroll
    for (int ct = 0; ct < 2; ct++) {
        int n = (2 * w + ct) * 16 + lr;
        #pragma unroll
        for (int kt = 0; kt < 4; kt++)
            b3f[ct][kt] = __builtin_bit_cast(bf16x8, *(const u32x4*)(&W3t[n * 128 + kt * 32 + q * 8]));
        b3v[ct] = b3[n];
    }

    const int G = (int)gridDim.x;
    int tb = blockIdx.x;
    int sel = 0;

    int2 pcur[4];
    u32x4 gb_r[4];
    {
        int eb = tb * 64;
        #pragma unroll
        for (int it = 0; it < 4; it++) pcur[it] = spair[eb + tr + 16 * it];
        #pragma unroll
        for (int it = 0; it < 4; it++)
            gb_r[it] = *(const u32x4*)(&gB[(size_t)pcur[it].x * DIM + c]);
    }

    for (; tb < NTILES; tb += G) {
        #pragma unroll
        for (int it = 0; it < 4; it++) {
            int t = tr + 16 * it;
            u32x4 ga = *(const u32x4*)(&gA[(size_t)pcur[it].y * DIM + c]);
            u32x4 m;
            #pragma unroll
            for (int jj = 0; jj < 4; jj++)
                m[jj] = bf2_add_relu(ga[jj], gb_r[it][jj]);
            *(u32x4*)(&m1_lds[t * 136 + c]) = m;
        }
        if ((tid & 15) == 0) {
            #pragma unroll
            for (int it = 0; it < 4; it++) s_dst[sel][tr + 16 * it] = pcur[it].y;
        }
        __syncthreads();   // (1) m1 + s_dst ready; also orders segmax(t-1) before m2 writes(t)

        int nx = tb + G;
        int2 pnx[4];
        if (nx < NTILES) {
            int eb = nx * 64;
            #pragma unroll
            for (int it = 0; it < 4; it++) pnx[it] = spair[eb + tr + 16 * it];
            #pragma unroll
            for (int it = 0; it < 4; it++)
                gb_r[it] = *(const u32x4*)(&gB[(size_t)pnx[it].x * DIM + c]);
        }

        f32x4 acc2[4][2];
        #pragma unroll
        for (int rt = 0; rt < 4; rt++)
            #pragma unroll
            for (int ct = 0; ct < 2; ct++) acc2[rt][ct] = (f32x4){0.f, 0.f, 0.f, 0.f};
        #pragma unroll
        for (int kt = 0; kt < 4; kt++) {
            #pragma unroll
            for (int rt = 0; rt < 4; rt++) {
                bf16x8 a = __builtin_bit_cast(bf16x8,
                    *(const u32x4*)(&m1_lds[(rt * 16 + lr) * 136 + kt * 32 + q * 8]));
                acc2[rt][0] = __builtin_amdgcn_mfma_f32_16x16x32_bf16(a, b3f[0][kt], acc2[rt][0], 0, 0, 0);
                acc2[rt][1] = __builtin_amdgcn_mfma_f32_16x16x32_bf16(a, b3f[1][kt], acc2[rt][1], 0, 0, 0);
            }
        }
        #pragma unroll
        for (int rt = 0; rt < 4; rt++) {
            #pragma unroll
            for (int ct = 0; ct < 2; ct++) {
                int col = (2 * w + ct) * 16 + lr;
                #pragma unroll
                for (int r = 0; r < 4; r++)
                    m2_lds[(rt * 16 + q * 4 + r) * 136 + col] = f2bf_hw(fmaxf(acc2[rt][ct][r] + b3v[ct], 0.f));
            }
        }
        __syncthreads();   // (2) m2 ready

        if (tid < 128) {
            int pair = tid & 63;
            int g = tid >> 6;                           // == wave index (0 or 1)
            const unsigned* m2p = (const unsigned*)m2_lds;   // [64][68] dwords
            int r0 = g * 32;
            unsigned cur = m2p[r0 * 68 + pair];
            int d = s_dst[sel][r0];                     // wave-uniform
            #pragma unroll 4
            for (int i = 1; i < 32; i++) {
                int dn = s_dst[sel][r0 + i];            // wave-uniform
                unsigned v = m2p[(r0 + i) * 68 + pair];
                if (dn != d) {                          // wave-uniform branch
                    atomicMax(&out[(size_t)d * DIM + 2 * pair],     (cur & 0xffffu) << 16);
                    atomicMax(&out[(size_t)d * DIM + 2 * pair + 1], cur & 0xffff0000u);
                    d = dn; cur = v;
                } else {
                    s16x2 a2 = __builtin_bit_cast(s16x2, cur);
                    s16x2 b2 = __builtin_bit_cast(s16x2, v);
                    cur = __builtin_bit_cast(unsigned, __builtin_elementwise_max(a2, b2));
                }
            }
            atomicMax(&out[(size_t)d * DIM + 2 * pair],     (cur & 0xffffu) << 16);
            atomicMax(&out[(size_t)d * DIM + 2 * pair + 1], cur & 0xffff0000u);
        }
        // no trailing barrier: next iter's m1/s_dst[sel^1] writes don't touch m2/s_dst[sel];
        // waves 2-3 run ahead into the next staging while waves 0-1 finish segmax.

        sel ^= 1;
        #pragma unroll
        for (int it = 0; it < 4; it++) pcur[it] = pnx[it];
    }
}

extern "C" void kernel_launch(void* const* d_in, const int* in_sizes, int n_in,
                              void* d_out, int out_size, void* d_ws, size_t ws_size,
                              hipStream_t stream) {
    const float* x  = (const float*)d_in[0];
    const int* eidx = (const int*)d_in[1];
    const float* W1 = (const float*)d_in[2];
    const float* b1 = (const float*)d_in[3];
    const float* W2 = (const float*)d_in[4];
    const float* b2 = (const float*)d_in[5];
    const float* W3 = (const float*)d_in[6];
    const float* b3 = (const float*)d_in[7];

    char* ws = (char*)d_ws;
    unsigned short* gA  = (unsigned short*)ws;                     // 12,800,000 B
    unsigned short* gB  = (unsigned short*)(ws + 12800000);        // 12,800,000 B
    unsigned short* W1t = (unsigned short*)(ws + 25600000);        // 32,768 B
    unsigned short* Wat = (unsigned short*)(ws + 25632768);        // 32,768 B
    unsigned short* Wbt = (unsigned short*)(ws + 25665536);        // 32,768 B
    unsigned short* W3t = (unsigned short*)(ws + 25698304);        // 32,768 B
    int* counts         = (int*)(ws + 25731072);                   // 262,144 B [bin][block]
    int* binsum         = (int*)(ws + 25993216);                   // 1,024 B
    int* binbase        = (int*)(ws + 25994240);                   // 2,048 B (NBIN+1 used)
    int2* spair         = (int2*)(ws + 25996288);                  // 6,400,000 B -> 32,396,288 total

    weights_kernel<<<256, 256, 0, stream>>>(W1, W2, W3, W1t, Wat, Wbt, W3t);
    fused_kernel<<<NODE_B + CNT_B + OUTZ_B, 256, 0, stream>>>(eidx, counts,
        x, W1t, Wat, Wbt, b1, b2, gA, gB, (u32x4*)d_out);
    scanA_kernel<<<NBIN, 256, 0, stream>>>(counts, binsum);
    scanB_kernel<<<1, 256, 0, stream>>>(binsum, binbase);
    cscatter_kernel<<<CNT_B, 256, 0, stream>>>(eidx, counts, binbase, spair);
    bsort_kernel<<<NBIN, 256, 0, stream>>>(binbase, spair);
    edge_kernel<<<2048, 256, 0, stream>>>(gA, gB, spair, W3t, b3, (unsigned int*)d_out);
}